// Round 5
// baseline (108.693 us; speedup 1.0000x reference)
//
#include <hip/hip_runtime.h>
#include <hip/hip_bf16.h>

// Problem constants (from reference)
#define BATCH    2048
#define N_LABELS 10000
#define HIDDEN   768
#define N_EDGES  20000
#define PENALTY  1e-4f

constexpr int THREADS   = 256;
constexpr int N4        = BATCH * N_LABELS / 4;   // 5,120,000 float4 pairs
constexpr int BCE_K     = 10;                     // float4s per thread
constexpr int BCE_STRIDE = N4 / BCE_K;            // 512,000 threads
constexpr int BCE_BLOCKS = BCE_STRIDE / THREADS;  // 2000 (exact, no tail)
constexpr int EDGES_PER_BLOCK = THREADS / 64;     // 4 waves -> 4 edges/block
constexpr int REG_BLOCKS = N_EDGES / EDGES_PER_BLOCK;     // 5000
constexpr int TOTAL_BLOCKS = BCE_BLOCKS + REG_BLOCKS;     // 7000 = 1000 * (2+5)

// stable softplus(x) - t*x via raw HW transcendentals:
// softplus(x) = max(x,0) + ln2 * log2(1 + 2^(-|x|*log2e))
__device__ __forceinline__ float bce_term(float x, float t) {
    float e = __builtin_amdgcn_exp2f(fabsf(x) * -1.44269504f); // e^{-|x|}
    float l = __builtin_amdgcn_logf(1.0f + e);                 // log2(1+e)
    return fmaxf(x, 0.0f) + 0.69314718f * l - t * x;
}

__device__ __forceinline__ float wave_reduce(float v) {
#pragma unroll
    for (int o = 32; o > 0; o >>= 1) v += __shfl_down(v, o, 64);
    return v;
}

// One kernel, roles interleaved: every group of 7 blocks = 2 BCE + 5 reg, so
// the latency-bound reg gathers overlap the BW-bound BCE stream throughout
// the dispatch instead of running as a tail (round-4 lesson). Each block
// atomicAdds its pre-scaled partial into out[0] — kills the finalize kernel
// and one launch gap; 7000 atomics to one line is contention-free.
__global__ void __launch_bounds__(THREADS)
fused_kernel(const float4* __restrict__ x4, const float4* __restrict__ t4,
             const float* __restrict__ params, const int* __restrict__ pidx,
             const int* __restrict__ cidx, float* __restrict__ out) {
    const int lane = threadIdx.x & 63;
    const int w    = threadIdx.x >> 6;
    __shared__ float s[THREADS / 64];

    const int g = blockIdx.x / 7;
    const int r = blockIdx.x - g * 7;

    float acc = 0.0f;
    float scale;
    if (r < 2) {
        // ---------- BCE: mean(softplus(x) - t*x) ----------
        const int tid = (g * 2 + r) * THREADS + threadIdx.x;
        float4 xs[BCE_K], ts[BCE_K];
#pragma unroll
        for (int j = 0; j < BCE_K; ++j) {
            xs[j] = x4[tid + j * BCE_STRIDE];
            ts[j] = t4[tid + j * BCE_STRIDE];
        }
#pragma unroll
        for (int j = 0; j < BCE_K; ++j) {
            acc += bce_term(xs[j].x, ts[j].x) + bce_term(xs[j].y, ts[j].y) +
                   bce_term(xs[j].z, ts[j].z) + bce_term(xs[j].w, ts[j].w);
        }
        scale = 1.0f / ((float)BATCH * (float)N_LABELS);
    } else {
        // ---- reg: 0.5*PENALTY * sum ||params[p]-params[c]||^2, 1 wave/edge ----
        const int edge = (g * 5 + (r - 2)) * EDGES_PER_BLOCK + w;
        const int p = pidx[edge];
        const int c = cidx[edge];
        const float4* rp = (const float4*)(params + (size_t)p * HIDDEN);
        const float4* rc = (const float4*)(params + (size_t)c * HIDDEN);

        float4 a[3], b[3];
#pragma unroll
        for (int j = 0; j < 3; ++j) a[j] = rp[j * 64 + lane];
#pragma unroll
        for (int j = 0; j < 3; ++j) b[j] = rc[j * 64 + lane];

#pragma unroll
        for (int j = 0; j < 3; ++j) {
            float dx = a[j].x - b[j].x, dy = a[j].y - b[j].y;
            float dz = a[j].z - b[j].z, dw = a[j].w - b[j].w;
            acc = fmaf(dx, dx, acc);
            acc = fmaf(dy, dy, acc);
            acc = fmaf(dz, dz, acc);
            acc = fmaf(dw, dw, acc);
        }
        scale = 0.5f * PENALTY;
    }

    acc = wave_reduce(acc);
    if (lane == 0) s[w] = acc;
    __syncthreads();
    if (threadIdx.x == 0) {
        atomicAdd(out, (s[0] + s[1] + s[2] + s[3]) * scale);
    }
}

extern "C" void kernel_launch(void* const* d_in, const int* in_sizes, int n_in,
                              void* d_out, int out_size, void* d_ws, size_t ws_size,
                              hipStream_t stream) {
    const float* logits  = (const float*)d_in[0];
    const float* targets = (const float*)d_in[1];
    const float* params  = (const float*)d_in[2];
    const int*   pidx    = (const int*)d_in[3];
    const int*   cidx    = (const int*)d_in[4];
    float* out = (float*)d_out;

    hipMemsetAsync(d_out, 0, sizeof(float), stream);
    fused_kernel<<<TOTAL_BLOCKS, THREADS, 0, stream>>>(
        (const float4*)logits, (const float4*)targets, params, pidx, cidx, out);
}